// Round 7
// baseline (297.909 us; speedup 1.0000x reference)
//
#include <hip/hip_runtime.h>
#include <hip/hip_bf16.h>

typedef __attribute__((ext_vector_type(8))) short short8;
typedef __attribute__((ext_vector_type(4))) float f32x4;

#define DEV __device__ __forceinline__
#define AS1 __attribute__((address_space(1)))
#define AS3 __attribute__((address_space(3)))

DEV float bf2f(unsigned short u) {
    union { unsigned int i; float f; } v;
    v.i = ((unsigned int)u) << 16;
    return v.f;
}
DEV unsigned short f2bf(float f) {
    union { float f; unsigned int i; } v; v.f = f;
    unsigned int r = v.i + 0x7FFFu + ((v.i >> 16) & 1u);
    return (unsigned short)(r >> 16);
}
DEV float sigmoidf_(float x) {
    return 1.0f / (1.0f + __expf(-x));
}

// ---------------------------------------------------------------------------
// 1. fp32 -> bf16: build xh[8192][2048] = [x|h] and xr[8192][2048] = [x|rh-slot]
//    (x half duplicated into xr; rh half filled later by gemm1's epilogue)
// ---------------------------------------------------------------------------
__global__ void conv_xh(const float* __restrict__ x, const float* __restrict__ h,
                        unsigned short* __restrict__ xh, unsigned short* __restrict__ xr)
{
    const int nX = 8192 * 1024 / 8;
    int i = blockIdx.x * blockDim.x + threadIdx.x;
    const float* src; int off;
    bool isx = i < nX;
    if (isx) { src = x; off = i * 8; }
    else     { src = h; off = (i - nX) * 8; }
    int row = off >> 10, col = off & 1023;
    float4 a = *(const float4*)(src + off);
    float4 b = *(const float4*)(src + off + 4);
    union { uint4 v; unsigned short s[8]; } o;
    o.s[0]=f2bf(a.x); o.s[1]=f2bf(a.y); o.s[2]=f2bf(a.z); o.s[3]=f2bf(a.w);
    o.s[4]=f2bf(b.x); o.s[5]=f2bf(b.y); o.s[6]=f2bf(b.z); o.s[7]=f2bf(b.w);
    if (isx) {
        *(uint4*)(xh + (size_t)row*2048 + col) = o.v;
        *(uint4*)(xr + (size_t)row*2048 + col) = o.v;
    } else {
        *(uint4*)(xh + (size_t)row*2048 + 1024 + col) = o.v;
    }
}

// ---------------------------------------------------------------------------
// 2. transpose + convert weights into the two fused B^T layouts
//    B1t [2048][2048]: n<1024 z (Wiz|Uhz), n>=1024 r (Wir|Uhr); k<1024 W, else U
//    B3t [1024][2048]: k<1024 Win, k>=1024 Uhn
// ---------------------------------------------------------------------------
__global__ void tconv(const float* __restrict__ Wiz, const float* __restrict__ Uhz,
                      const float* __restrict__ Wir, const float* __restrict__ Uhr,
                      const float* __restrict__ Win, const float* __restrict__ Uhn,
                      unsigned short* __restrict__ B1t, unsigned short* __restrict__ B3t)
{
    __shared__ float lds[32][33];
    const float* src; unsigned short* dst;
    switch (blockIdx.z) {
        case 0: src=Wiz; dst=B1t;                            break;
        case 1: src=Uhz; dst=B1t + 1024;                     break;
        case 2: src=Wir; dst=B1t + (size_t)1024*2048;        break;
        case 3: src=Uhr; dst=B1t + (size_t)1024*2048 + 1024; break;
        case 4: src=Win; dst=B3t;                            break;
        default: src=Uhn; dst=B3t + 1024;                    break;
    }
    int k0 = blockIdx.x * 32, n0 = blockIdx.y * 32;
    int tx = threadIdx.x & 31, ty = threadIdx.x >> 5;
    #pragma unroll
    for (int i = 0; i < 4; i++)
        lds[ty + 8*i][tx] = src[(size_t)(k0 + ty + 8*i)*1024 + n0 + tx];
    __syncthreads();
    #pragma unroll
    for (int i = 0; i < 4; i++)
        dst[(size_t)(n0 + ty + 8*i)*2048 + k0 + tx] = f2bf(lds[tx][ty + 8*i]);
}

// ---------------------------------------------------------------------------
// 3. GEMM1: 256x256 tile, BK=64, 8 waves (2Mx4N), 8-phase pipeline
//    (T2 swizzle + T3/T4 counted vmcnt + T5 setprio + compact XCD map).
//    A = xh [8192][2048] (single matrix now). Bt = B1t [2048][2048].
//    All staging addresses precomputed per-thread; stage = base + KT*64.
// ---------------------------------------------------------------------------
#define GLD(SRC,DST) __builtin_amdgcn_global_load_lds(                        \
    (const AS1 void*)(SRC), (AS3 void*)(DST), 16, 0, 0)
#define STAGE_A(BUF,BAND,KT)                                                  \
    GLD(gA##BAND##0 + (size_t)(KT)*64, smA + (BUF)*32768 + (BAND)*16384);     \
    GLD(gA##BAND##1 + (size_t)(KT)*64, smA + (BUF)*32768 + (BAND)*16384 + 8192);
#define STAGE_B(BUF,BAND,KT)                                                  \
    GLD(gB##BAND##0 + (size_t)(KT)*64, smB + (BUF)*32768 + (BAND)*16384);     \
    GLD(gB##BAND##1 + (size_t)(KT)*64, smB + (BUF)*32768 + (BAND)*16384 + 8192);

#define LOAD_A(BUF,MH)                                                        \
    { _Pragma("unroll") for (int mi = 0; mi < 4; mi++)                        \
      { _Pragma("unroll") for (int ks = 0; ks < 2; ks++)                      \
        af[mi][ks] = *(const short8*)(smem + (BUF)*32768 + (MH)*16384         \
                        + arow + mi*2048 + ((((ks<<2)|lk)<<4) ^ aswz)); } }
#define LOAD_B(BUF,NH,DST)                                                    \
    { _Pragma("unroll") for (int ni = 0; ni < 2; ni++)                        \
      { _Pragma("unroll") for (int ks = 0; ks < 2; ks++)                      \
        DST[ni][ks] = *(const short8*)(smem + (BUF)*32768 + (NH)*16384        \
                        + brow + ni*2048 + ((((ks<<2)|lk)<<4) ^ aswz)); } }
// ks OUTER: 8 independent MFMAs per k-slice (no back-to-back acc dependency)
#define MM(MH,NH,BF)                                                          \
    { _Pragma("unroll") for (int ks = 0; ks < 2; ks++)                        \
      { _Pragma("unroll") for (int mi = 0; mi < 4; mi++)                      \
        { _Pragma("unroll") for (int ni = 0; ni < 2; ni++)                    \
          acc[(MH)*4+mi][(NH)*2+ni] = __builtin_amdgcn_mfma_f32_16x16x32_bf16(\
              af[mi][ks], BF[ni][ks], acc[(MH)*4+mi][(NH)*2+ni], 0, 0, 0); } } }
#define PH_MID(DO_VM)                                                         \
    if (DO_VM) asm volatile("s_waitcnt vmcnt(6)" ::: "memory");               \
    __builtin_amdgcn_s_barrier();                                             \
    asm volatile("s_waitcnt lgkmcnt(0)" ::: "memory");                        \
    __builtin_amdgcn_s_setprio(1);
#define PH_END                                                                \
    __builtin_amdgcn_s_setprio(0);                                            \
    __builtin_amdgcn_s_barrier();

__global__ __launch_bounds__(512, 2)
void gemm1_8ph(const unsigned short* __restrict__ xh,   // [8192][2048]
               const unsigned short* __restrict__ Bt,   // B1t [2048][2048]
               const float* __restrict__ bz, const float* __restrict__ br,
               const float* __restrict__ hsrc,
               float* __restrict__ zbuf, unsigned short* __restrict__ xr)
{
    extern __shared__ char smem[];
    const int tid = threadIdx.x;

    // compact per-XCD 8Mx4N tile block (dispatch round-robins bid across XCDs)
    const int bid = blockIdx.x;
    const int xcd = bid & 7, j = bid >> 3;
    const int mt  = (xcd >> 1) * 8 + (j >> 2);
    const int nt  = (xcd & 1) * 4 + (j & 3);
    const int gm = mt * 256, gn = nt * 256;

    const int w  = tid >> 6, l = tid & 63;
    const int wr = w >> 2, wc = w & 3;
    const int lr = l & 15, lk = l >> 4;

    const int arow = wr*8192 + lr*128;
    const int brow = 65536 + wc*4096 + lr*128;
    const int aswz = (lr & 7) << 4;

    // ---- precomputed staging addresses (T2 inverse swizzle on global k) ----
    const int s   = tid >> 3;                       // row-pair within band, j=0
    const int kel = ((tid & 7) ^ (s & 7)) << 3;     // inverse-swizzled k elems
    char* smA = smem + tid * 16;
    char* smB = smem + 65536 + tid * 16;
    const unsigned short* gA00 = xh + (size_t)(gm +        s      )*2048 + kel;
    const unsigned short* gA01 = xh + (size_t)(gm + 128 +  s      )*2048 + kel;
    const unsigned short* gA10 = xh + (size_t)(gm +  64 +  s      )*2048 + kel;
    const unsigned short* gA11 = xh + (size_t)(gm + 192 +  s      )*2048 + kel;
    const int nb = ((s >> 5) << 6) | (s & 31);
    const unsigned short* gB00 = Bt + (size_t)(gn +       nb      )*2048 + kel;
    const unsigned short* gB01 = Bt + (size_t)(gn + 128 + nb      )*2048 + kel;
    const unsigned short* gB10 = Bt + (size_t)(gn +  32 + nb      )*2048 + kel;
    const unsigned short* gB11 = Bt + (size_t)(gn + 160 + nb      )*2048 + kel;

    f32x4 acc[8][4] = {};
    short8 af[4][2], bf0[2][2], bf1[2][2];

    // prologue: tile0 (4 bands) + tile1 (3 bands); drain tile0 (vmcnt 6 = 3 bands)
    STAGE_A(0,0,0); STAGE_A(0,1,0); STAGE_B(0,0,0); STAGE_B(0,1,0);
    STAGE_A(1,0,1); STAGE_B(1,0,1); STAGE_B(1,1,1);
    asm volatile("s_waitcnt vmcnt(6)" ::: "memory");
    __builtin_amdgcn_s_barrier();

    for (int it = 0; it < 16; ++it) {
        const int T  = 2 * it;
        const int t1 = (T+1 < 31) ? T+1 : 31;
        const int t2 = (T+2 < 31) ? T+2 : 31;
        const int t3 = (T+3 < 31) ? T+3 : 31;

        // ---- tile T in buf0 ----
        LOAD_A(0,0); LOAD_B(0,0,bf0);
        STAGE_A(1,1,t1);
        PH_MID(false); MM(0,0,bf0); PH_END;

        LOAD_B(0,1,bf1);
        STAGE_A(0,0,t2);
        PH_MID(false); MM(0,1,bf1); PH_END;

        LOAD_A(0,1);
        STAGE_B(0,0,t2);
        PH_MID(false); MM(1,0,bf0); PH_END;

        STAGE_B(0,1,t2);
        PH_MID(true); MM(1,1,bf1); PH_END;

        // ---- tile T+1 in buf1 ----
        LOAD_A(1,0); LOAD_B(1,0,bf0);
        STAGE_A(0,1,t2);
        PH_MID(false); MM(0,0,bf0); PH_END;

        LOAD_B(1,1,bf1);
        STAGE_A(1,0,t3);
        PH_MID(false); MM(0,1,bf1); PH_END;

        LOAD_A(1,1);
        STAGE_B(1,0,t3);
        PH_MID(false); MM(1,0,bf0); PH_END;

        STAGE_B(1,1,t3);
        PH_MID(true); MM(1,1,bf1); PH_END;
    }

    // epilogue: C/D layout col=lane&15, row=(lane>>4)*4+reg (m89/m91)
    #pragma unroll
    for (int Mi = 0; Mi < 8; Mi++) {
        #pragma unroll
        for (int jj = 0; jj < 4; jj++) {
            int row = gm + wr*128 + Mi*16 + lk*4 + jj;
            #pragma unroll
            for (int Ni = 0; Ni < 4; Ni++) {
                int col = gn + wc*64 + Ni*16 + lr;
                float v = acc[Mi][Ni][jj];
                if (col < 1024) {
                    zbuf[(size_t)row*1024 + col] = sigmoidf_(v + bz[col]);
                } else {
                    int c = col - 1024;
                    float rv = sigmoidf_(v + br[c]);
                    xr[(size_t)row*2048 + 1024 + c] =
                        f2bf(rv * hsrc[(size_t)row*1024 + c]);
                }
            }
        }
    }
}

// ---------------------------------------------------------------------------
// 4. GEMM2 (verified m97 structure): xr @ [[Win],[Uhn]] + GRU epilogue
//    A = xr [8192][2048] single matrix (row stride 2048).
// ---------------------------------------------------------------------------
__global__ __launch_bounds__(256, 2)
void gemm2_m97(const unsigned short* __restrict__ A,
               const unsigned short* __restrict__ Bt,
               const float* __restrict__ bn,
               const float* __restrict__ hsrc,
               const float* __restrict__ zbuf,
               float* __restrict__ out)
{
    __shared__ unsigned short lA[128*32];
    __shared__ unsigned short lB[128*32];
    const int tid = threadIdx.x;
    const int gm = blockIdx.x * 128, gn = blockIdx.y * 128;

    const int w  = tid >> 6, l = tid & 63;
    const int wm = (w >> 1) * 64, wn = (w & 1) * 64;
    const int lr = l & 15, lk = l >> 4;

    f32x4 acc[4][4] = {};

    const int srow = tid >> 2;
    const int scol = (tid & 3) * 8;
    char* lAp = (char*)lA + tid * 16;
    char* lBp = (char*)lB + tid * 16;

    const unsigned short* Ab0 = A  + (size_t)(gm + srow) * 2048 + scol;
    const unsigned short* Bb0 = Bt + (size_t)(gn + srow) * 2048 + scol;

    for (int kt = 0; kt < 2048; kt += 32) {
        __syncthreads();
        GLD(Ab0 + kt,                     lAp);
        GLD(Ab0 + kt + (size_t)64*2048,   lAp + 4096);
        GLD(Bb0 + kt,                     lBp);
        GLD(Bb0 + kt + (size_t)64*2048,   lBp + 4096);
        __syncthreads();

        short8 af[4], bfr[4];
        #pragma unroll
        for (int mi = 0; mi < 4; mi++)
            af[mi] = *(const short8*)&lA[(wm + mi*16 + lr)*32 + lk*8];
        #pragma unroll
        for (int ni = 0; ni < 4; ni++)
            bfr[ni] = *(const short8*)&lB[(wn + ni*16 + lr)*32 + lk*8];
        #pragma unroll
        for (int mi = 0; mi < 4; mi++)
            #pragma unroll
            for (int ni = 0; ni < 4; ni++)
                acc[mi][ni] = __builtin_amdgcn_mfma_f32_16x16x32_bf16(
                    af[mi], bfr[ni], acc[mi][ni], 0, 0, 0);
    }

    #pragma unroll
    for (int mi = 0; mi < 4; mi++) {
        #pragma unroll
        for (int j = 0; j < 4; j++) {
            int row = gm + wm + mi*16 + lk*4 + j;
            #pragma unroll
            for (int ni = 0; ni < 4; ni++) {
                int col = gn + wn + ni*16 + lr;
                float nv = sigmoidf_(acc[mi][ni][j] + bn[col]);
                float zv = zbuf[(size_t)row*1024 + col];
                float hv = hsrc[(size_t)row*1024 + col];
                out[(size_t)row*1024 + col] = (1.0f - zv)*hv + zv*nv;
            }
        }
    }
}

// ---------------------------------------------------------------------------
extern "C" void kernel_launch(void* const* d_in, const int* in_sizes, int n_in,
                              void* d_out, int out_size, void* d_ws, size_t ws_size,
                              hipStream_t stream)
{
    const float* x   = (const float*)d_in[0];
    const float* h   = (const float*)d_in[1];
    const float* Wiz = (const float*)d_in[2];
    const float* Uhz = (const float*)d_in[3];
    const float* bz  = (const float*)d_in[4];
    const float* Wir = (const float*)d_in[5];
    const float* Uhr = (const float*)d_in[6];
    const float* br  = (const float*)d_in[7];
    const float* Win = (const float*)d_in[8];
    const float* Uhn = (const float*)d_in[9];
    const float* bn  = (const float*)d_in[10];
    float* out = (float*)d_out;

    char* ws = (char*)d_ws;
    const size_t MB = 1024ull * 1024ull;
    unsigned short* xh   = (unsigned short*)(ws + 0);        // 32 MB [8192][2048]
    unsigned short* xr   = (unsigned short*)(ws + 32*MB);    // 32 MB [8192][2048]
    unsigned short* B1t  = (unsigned short*)(ws + 64*MB);    //  8 MB [2048][2048]
    unsigned short* B3t  = (unsigned short*)(ws + 72*MB);    //  4 MB [1024][2048]
    float*          zbuf = (float*)(ws + 76*MB);             // 32 MB -> total 108 MB

    (void)hipFuncSetAttribute((const void*)gemm1_8ph,
                              hipFuncAttributeMaxDynamicSharedMemorySize, 131072);

    conv_xh<<<dim3(8192), dim3(256), 0, stream>>>(x, h, xh, xr);

    tconv<<<dim3(32, 32, 6), dim3(256), 0, stream>>>(
        Wiz, Uhz, Wir, Uhr, Win, Uhn, B1t, B3t);

    // [x|h] @ [[Wiz|Wir],[Uhz|Uhr]] with fused z/r epilogue (8-phase 256^2)
    gemm1_8ph<<<dim3(256), dim3(512), 131072, stream>>>(
        xh, B1t, bz, br, h, zbuf, xr);

    // [x|rh] @ [[Win],[Uhn]] with fused GRU output epilogue (m97 structure)
    gemm2_m97<<<dim3(64, 8), dim3(256), 0, stream>>>(
        xr, B3t, bn, h, zbuf, out);
}

// Round 9
// 294.068 us; speedup vs baseline: 1.0131x; 1.0131x over previous
//
#include <hip/hip_runtime.h>
#include <hip/hip_bf16.h>

typedef __attribute__((ext_vector_type(8))) short short8;
typedef __attribute__((ext_vector_type(4))) float f32x4;

#define DEV __device__ __forceinline__
#define AS1 __attribute__((address_space(1)))
#define AS3 __attribute__((address_space(3)))

DEV float bf2f(unsigned short u) {
    union { unsigned int i; float f; } v;
    v.i = ((unsigned int)u) << 16;
    return v.f;
}
DEV unsigned short f2bf(float f) {
    union { float f; unsigned int i; } v; v.f = f;
    unsigned int r = v.i + 0x7FFFu + ((v.i >> 16) & 1u);
    return (unsigned short)(r >> 16);
}
DEV float sigmoidf_(float x) {
    return 1.0f / (1.0f + __expf(-x));
}

#define GLD(SRC,DST) __builtin_amdgcn_global_load_lds(                        \
    (const AS1 void*)(SRC), (AS3 void*)(DST), 16, 0, 0)

// ---------------------------------------------------------------------------
// 1. fp32 -> bf16: build xh[8192][2048] = [x|h]
// ---------------------------------------------------------------------------
__global__ void conv_xh(const float* __restrict__ x, const float* __restrict__ h,
                        unsigned short* __restrict__ xh)
{
    const int nX = 8192 * 1024 / 8;
    int i = blockIdx.x * blockDim.x + threadIdx.x;
    const float* src; int off, base;
    if (i < nX) { src = x; off = i * 8;        base = 0;    }
    else        { src = h; off = (i - nX) * 8; base = 1024; }
    int row = off >> 10, col = off & 1023;
    float4 a = *(const float4*)(src + off);
    float4 b = *(const float4*)(src + off + 4);
    union { uint4 v; unsigned short s[8]; } o;
    o.s[0]=f2bf(a.x); o.s[1]=f2bf(a.y); o.s[2]=f2bf(a.z); o.s[3]=f2bf(a.w);
    o.s[4]=f2bf(b.x); o.s[5]=f2bf(b.y); o.s[6]=f2bf(b.z); o.s[7]=f2bf(b.w);
    *(uint4*)(xh + (size_t)row*2048 + base + col) = o.v;
}

// ---------------------------------------------------------------------------
// 2. transpose + convert weights into the two fused B^T layouts
//    B1t [2048][2048]: n<1024 z (Wiz|Uhz), n>=1024 r (Wir|Uhr); k<1024 W, else U
//    B3t [1024][2048]: k<1024 Win, k>=1024 Uhn
// ---------------------------------------------------------------------------
__global__ void tconv(const float* __restrict__ Wiz, const float* __restrict__ Uhz,
                      const float* __restrict__ Wir, const float* __restrict__ Uhr,
                      const float* __restrict__ Win, const float* __restrict__ Uhn,
                      unsigned short* __restrict__ B1t, unsigned short* __restrict__ B3t)
{
    __shared__ float lds[32][33];
    const float* src; unsigned short* dst;
    switch (blockIdx.z) {
        case 0: src=Wiz; dst=B1t;                            break;
        case 1: src=Uhz; dst=B1t + 1024;                     break;
        case 2: src=Wir; dst=B1t + (size_t)1024*2048;        break;
        case 3: src=Uhr; dst=B1t + (size_t)1024*2048 + 1024; break;
        case 4: src=Win; dst=B3t;                            break;
        default: src=Uhn; dst=B3t + 1024;                    break;
    }
    int k0 = blockIdx.x * 32, n0 = blockIdx.y * 32;
    int tx = threadIdx.x & 31, ty = threadIdx.x >> 5;
    #pragma unroll
    for (int i = 0; i < 4; i++)
        lds[ty + 8*i][tx] = src[(size_t)(k0 + ty + 8*i)*1024 + n0 + tx];
    __syncthreads();
    #pragma unroll
    for (int i = 0; i < 4; i++)
        dst[(size_t)(n0 + ty + 8*i)*2048 + k0 + tx] = f2bf(lds[tx][ty + 8*i]);
}

// ---------------------------------------------------------------------------
// 3. GEMM1, m97 structure (verified 731 TF at this M in R1): 128x128 tile,
//    BK=32, 4 waves, K=2048. A = xh [8192][2048]. Bt = B1t [2048][2048].
//    Fused z/r epilogue: zb (bf16), rh (bf16; h read from xh's bf16 half).
// ---------------------------------------------------------------------------
__global__ __launch_bounds__(256, 2)
void gemm1_m97(const unsigned short* __restrict__ A,
               const unsigned short* __restrict__ Bt,
               const float* __restrict__ bz, const float* __restrict__ br,
               unsigned short* __restrict__ zb, unsigned short* __restrict__ rh)
{
    __shared__ unsigned short lA[128*32];
    __shared__ unsigned short lB[128*32];
    const int tid = threadIdx.x;
    const int gm = blockIdx.x * 128, gn = blockIdx.y * 128;

    const int w  = tid >> 6, l = tid & 63;
    const int wm = (w >> 1) * 64, wn = (w & 1) * 64;
    const int lr = l & 15, lk = l >> 4;

    f32x4 acc[4][4] = {};

    const int srow = tid >> 2;
    const int scol = (tid & 3) * 8;
    char* lAp = (char*)lA + tid * 16;
    char* lBp = (char*)lB + tid * 16;

    const unsigned short* Ab0 = A  + (size_t)(gm + srow) * 2048 + scol;
    const unsigned short* Bb0 = Bt + (size_t)(gn + srow) * 2048 + scol;

    for (int kt = 0; kt < 2048; kt += 32) {
        __syncthreads();
        GLD(Ab0 + kt,                   lAp);
        GLD(Ab0 + kt + (size_t)64*2048, lAp + 4096);
        GLD(Bb0 + kt,                   lBp);
        GLD(Bb0 + kt + (size_t)64*2048, lBp + 4096);
        __syncthreads();

        short8 af[4], bfr[4];
        #pragma unroll
        for (int mi = 0; mi < 4; mi++)
            af[mi] = *(const short8*)&lA[(wm + mi*16 + lr)*32 + lk*8];
        #pragma unroll
        for (int ni = 0; ni < 4; ni++)
            bfr[ni] = *(const short8*)&lB[(wn + ni*16 + lr)*32 + lk*8];
        #pragma unroll
        for (int mi = 0; mi < 4; mi++)
            #pragma unroll
            for (int ni = 0; ni < 4; ni++)
                acc[mi][ni] = __builtin_amdgcn_mfma_f32_16x16x32_bf16(
                    af[mi], bfr[ni], acc[mi][ni], 0, 0, 0);
    }

    // C/D layout (m89/m91 verified): col = lane&15, row = (lane>>4)*4 + reg
    #pragma unroll
    for (int mi = 0; mi < 4; mi++) {
        #pragma unroll
        for (int j = 0; j < 4; j++) {
            int row = gm + wm + mi*16 + lk*4 + j;
            #pragma unroll
            for (int ni = 0; ni < 4; ni++) {
                int col = gn + wn + ni*16 + lr;
                float v = acc[mi][ni][j];
                if (col < 1024) {
                    zb[(size_t)row*1024 + col] = f2bf(sigmoidf_(v + bz[col]));
                } else {
                    int c = col - 1024;
                    float rv = sigmoidf_(v + br[c]);
                    float hv = bf2f(A[(size_t)row*2048 + 1024 + c]);
                    rh[(size_t)row*1024 + c] = f2bf(rv * hv);
                }
            }
        }
    }
}

// ---------------------------------------------------------------------------
// 4. GEMM2, m97 structure, split-A: k<1024 -> xh's x half (stride 2048),
//    k>=1024 -> rh (stride 1024). B = B3t [1024][2048]. GRU output epilogue.
// ---------------------------------------------------------------------------
__global__ __launch_bounds__(256, 2)
void gemm2_m97(const unsigned short* __restrict__ xh,
               const unsigned short* __restrict__ rh,
               const unsigned short* __restrict__ Bt,
               const float* __restrict__ bn,
               const float* __restrict__ hsrc,
               const unsigned short* __restrict__ zb,
               float* __restrict__ out)
{
    __shared__ unsigned short lA[128*32];
    __shared__ unsigned short lB[128*32];
    const int tid = threadIdx.x;
    const int gm = blockIdx.x * 128, gn = blockIdx.y * 128;

    const int w  = tid >> 6, l = tid & 63;
    const int wm = (w >> 1) * 64, wn = (w & 1) * 64;
    const int lr = l & 15, lk = l >> 4;

    f32x4 acc[4][4] = {};

    const int srow = tid >> 2;
    const int scol = (tid & 3) * 8;
    char* lAp = (char*)lA + tid * 16;
    char* lBp = (char*)lB + tid * 16;

    const unsigned short* Ax = xh + (size_t)(gm + srow) * 2048 + scol;
    const unsigned short* Ar = rh + (size_t)(gm + srow) * 1024 + scol;
    const unsigned short* Bb = Bt + (size_t)(gn + srow) * 2048 + scol;

    for (int kt = 0; kt < 2048; kt += 32) {
        __syncthreads();
        if (kt < 1024) {
            GLD(Ax + kt,                   lAp);
            GLD(Ax + kt + (size_t)64*2048, lAp + 4096);
        } else {
            GLD(Ar + (kt - 1024),                   lAp);
            GLD(Ar + (kt - 1024) + (size_t)64*1024, lAp + 4096);
        }
        GLD(Bb + kt,                   lBp);
        GLD(Bb + kt + (size_t)64*2048, lBp + 4096);
        __syncthreads();

        short8 af[4], bfr[4];
        #pragma unroll
        for (int mi = 0; mi < 4; mi++)
            af[mi] = *(const short8*)&lA[(wm + mi*16 + lr)*32 + lk*8];
        #pragma unroll
        for (int ni = 0; ni < 4; ni++)
            bfr[ni] = *(const short8*)&lB[(wn + ni*16 + lr)*32 + lk*8];
        #pragma unroll
        for (int mi = 0; mi < 4; mi++)
            #pragma unroll
            for (int ni = 0; ni < 4; ni++)
                acc[mi][ni] = __builtin_amdgcn_mfma_f32_16x16x32_bf16(
                    af[mi], bfr[ni], acc[mi][ni], 0, 0, 0);
    }

    #pragma unroll
    for (int mi = 0; mi < 4; mi++) {
        #pragma unroll
        for (int j = 0; j < 4; j++) {
            int row = gm + wm + mi*16 + lk*4 + j;
            #pragma unroll
            for (int ni = 0; ni < 4; ni++) {
                int col = gn + wn + ni*16 + lr;
                float nv = sigmoidf_(acc[mi][ni][j] + bn[col]);
                float zv = bf2f(zb[(size_t)row*1024 + col]);
                float hv = hsrc[(size_t)row*1024 + col];
                out[(size_t)row*1024 + col] = (1.0f - zv)*hv + zv*nv;
            }
        }
    }
}

// ---------------------------------------------------------------------------
extern "C" void kernel_launch(void* const* d_in, const int* in_sizes, int n_in,
                              void* d_out, int out_size, void* d_ws, size_t ws_size,
                              hipStream_t stream)
{
    const float* x   = (const float*)d_in[0];
    const float* h   = (const float*)d_in[1];
    const float* Wiz = (const float*)d_in[2];
    const float* Uhz = (const float*)d_in[3];
    const float* bz  = (const float*)d_in[4];
    const float* Wir = (const float*)d_in[5];
    const float* Uhr = (const float*)d_in[6];
    const float* br  = (const float*)d_in[7];
    const float* Win = (const float*)d_in[8];
    const float* Uhn = (const float*)d_in[9];
    const float* bn  = (const float*)d_in[10];
    float* out = (float*)d_out;

    char* ws = (char*)d_ws;
    const size_t MB = 1024ull * 1024ull;
    unsigned short* xh   = (unsigned short*)(ws + 0);        // 32 MB [8192][2048]
    unsigned short* rh   = (unsigned short*)(ws + 32*MB);    // 16 MB [8192][1024]
    unsigned short* B1t  = (unsigned short*)(ws + 48*MB);    //  8 MB [2048][2048]
    unsigned short* B3t  = (unsigned short*)(ws + 56*MB);    //  4 MB [1024][2048]
    unsigned short* zb   = (unsigned short*)(ws + 60*MB);    // 16 MB -> total 76 MB

    // 1. x,h -> bf16 fused buffer
    conv_xh<<<dim3(8192), dim3(256), 0, stream>>>(x, h, xh);

    // 2. weights -> fused bf16 B^T layouts
    tconv<<<dim3(32, 32, 6), dim3(256), 0, stream>>>(
        Wiz, Uhz, Wir, Uhr, Win, Uhn, B1t, B3t);

    // 3. [x|h] @ [[Wiz|Wir],[Uhz|Uhr]] with fused z/r epilogue
    gemm1_m97<<<dim3(64, 16), dim3(256), 0, stream>>>(
        xh, B1t, bz, br, zb, rh);

    // 4. [x|rh] @ [[Win],[Uhn]] with fused GRU output epilogue
    gemm2_m97<<<dim3(64, 8), dim3(256), 0, stream>>>(
        xh, rh, B3t, bn, h, zb, out);
}